// Round 1
// baseline (758.554 us; speedup 1.0000x reference)
//
#include <hip/hip_runtime.h>
#include <cstdint>

// Problem constants
#define NROWS_HALF 32768          // rows 0..32767 pair with rows 32768..65535
#define NPTS 1000                 // coordinate codebook size
#define QC_OFF 4194304            // quantized_coord offset in d_out (floats)
#define LOSS_OFF 8388608          // loss offset in d_out (floats)

// ws layout (floats): [0,64000) vecsT[64][1000]; [64000,128000) vecs[1000][64];
// [128000,130048) M[32][64]; [130048] loss accumulator
#define WS_VECS 64000
#define WS_M 128000
#define WS_LOSS 130048

// ---------------- Threefry-2x32 (20 rounds), matches JAX ----------------
__host__ __device__ __forceinline__ void tf2x32(uint32_t k0, uint32_t k1,
                                                uint32_t x0, uint32_t x1,
                                                uint32_t& o0, uint32_t& o1) {
  const uint32_t k2 = k0 ^ k1 ^ 0x1BD11BDAu;
#define TF_R(r) { x0 += x1; x1 = (x1 << (r)) | (x1 >> (32 - (r))); x1 ^= x0; }
  x0 += k0; x1 += k1;
  TF_R(13) TF_R(15) TF_R(26) TF_R(6)
  x0 += k1; x1 += k2 + 1u;
  TF_R(17) TF_R(29) TF_R(16) TF_R(24)
  x0 += k2; x1 += k0 + 2u;
  TF_R(13) TF_R(15) TF_R(26) TF_R(6)
  x0 += k0; x1 += k1 + 3u;
  TF_R(17) TF_R(29) TF_R(16) TF_R(24)
  x0 += k1; x1 += k2 + 4u;
  TF_R(13) TF_R(15) TF_R(26) TF_R(6)
  x0 += k2; x1 += k0 + 5u;
#undef TF_R
  o0 = x0; o1 = x1;
}

// gumbel(bits) = -log(-log(u + 1e-20) + 1e-20), u = (bits>>9 | 1.0f) - 1.0f
// For u near 1 use exact-delta series: log(1-d) = -(d + d^2/2 + d^3/3), d exact.
__device__ __forceinline__ float gumbel_from_bits(uint32_t bits) {
  const uint32_t mant = bits >> 9;                       // 0 .. 2^23-1
  const float u = __uint_as_float(mant | 0x3f800000u) - 1.0f;
  const float delta = (float)(8388608u - mant) * 1.1920928955078125e-7f;
  float l;
  if (delta < 0.00390625f) {                             // u > ~0.996
    l = -(delta + 0.5f * delta * delta + 0.33333333f * delta * delta * delta);
  } else {
    l = __logf(u + 1e-20f);
  }
  return -__logf(-l + 1e-20f);
}

// ---------------- setup: vecs, vecsT, M, loss=0 ----------------
__global__ void setup_kernel(const float* __restrict__ lw, const float* __restrict__ lb,
                             const float* __restrict__ emb, const float* __restrict__ lws,
                             float* __restrict__ ws) {
  float* vecsT = ws;
  float* vecs  = ws + WS_VECS;
  float* M     = ws + WS_M;
  int idx = blockIdx.x * 256 + threadIdx.x;
  if (idx < 64000) {
    int n = idx >> 6, c = idx & 63;
    // np.meshgrid(x,x,x) 'xy': grid[n] = (x[(n/10)%10], x[n/100], x[n%10])
    int jx = (n / 10) % 10, iy = n / 100, kz = n % 10;
    const double step = 1.5 / 9.0;
    float gx = (float)(jx * step), gy = (float)(iy * step), gz = (float)(kz * step);
    float v = gx * lw[c * 3 + 0] + gy * lw[c * 3 + 1] + gz * lw[c * 3 + 2] + lb[c];
    vecs[n * 64 + c] = v;
    vecsT[c * 1000 + n] = v;
  } else if (idx < 66048) {
    int i2 = idx - 64000;
    int m = i2 >> 6, d = i2 & 63;     // m = k*8+n
    int k = m >> 3;
    float acc = 0.f;
    #pragma unroll
    for (int e = 0; e < 16; ++e) acc += emb[m * 16 + e] * lws[(k * 16 + e) * 64 + d];
    M[m * 64 + d] = acc;              // M[m][d] = sum_e embK[k,n,e]*lin_ws[k,e,d]
  } else if (idx == 66048) {
    ws[WS_LOSS] = 0.f;
  }
}

// ---------------- block reductions (2 values at once) ----------------
template <bool IS_MAX>
__device__ __forceinline__ void block_reduce2(float& a, float& b, float* scratch, int t) {
  #pragma unroll
  for (int off = 32; off > 0; off >>= 1) {
    float a2 = __shfl_xor(a, off);
    float b2 = __shfl_xor(b, off);
    if (IS_MAX) { a = fmaxf(a, a2); b = fmaxf(b, b2); }
    else        { a += a2;          b += b2;          }
  }
  const int w = t >> 6;
  __syncthreads();
  if ((t & 63) == 0) { scratch[w] = a; scratch[4 + w] = b; }
  __syncthreads();
  if (IS_MAX) {
    a = fmaxf(fmaxf(scratch[0], scratch[1]), fmaxf(scratch[2], scratch[3]));
    b = fmaxf(fmaxf(scratch[4], scratch[5]), fmaxf(scratch[6], scratch[7]));
  } else {
    a = (scratch[0] + scratch[1]) + (scratch[2] + scratch[3]);
    b = (scratch[4] + scratch[5]) + (scratch[6] + scratch[7]);
  }
}

// ---------------- fused main kernel ----------------
// 8192 blocks x 256 threads; block handles 4 row-pairs (rows pair0+p, pair0+p+32768)
__global__ __launch_bounds__(256) void fused_kernel(
    const float* __restrict__ inp, const float* __restrict__ emb,
    const float* __restrict__ ws, float* __restrict__ out,
    float* __restrict__ loss_acc,
    uint32_t kc0, uint32_t kc1, uint32_t kp0, uint32_t kp1) {
  const float* vecsT = ws;
  const float* vecs  = ws + WS_VECS;
  const float* M     = ws + WS_M;

  __shared__ float x_s[8][64];        // input rows (reused as q_s in phase 5b)
  __shared__ float xc_s[8][NPTS];     // logits, then gumbel weights
  __shared__ float xp_s[8][32];       // codebook logits
  __shared__ float red_s[8];
  __shared__ float invW_s[8];
  __shared__ float kl_s;

  const int t = threadIdx.x;
  const int pair0 = blockIdx.x * 4;

  if (t == 0) kl_s = 0.f;
  // ---- load 8 input rows ----
  #pragma unroll
  for (int it = 0; it < 2; ++it) {
    int idx = it * 256 + t;
    int rl = idx >> 6, d = idx & 63;
    int row = (rl < 4) ? (pair0 + rl) : (pair0 + rl - 4 + NROWS_HALF);
    x_s[rl][d] = inp[row * 64 + d];
  }
  __syncthreads();

  // ---- phase 2: logits xc = x . vecsT  (thread t covers n = 4t..4t+3) ----
  if (t < 250) {
    float acc0[8], acc1[8], acc2[8], acc3[8];
    #pragma unroll
    for (int rl = 0; rl < 8; ++rl) { acc0[rl] = 0.f; acc1[rl] = 0.f; acc2[rl] = 0.f; acc3[rl] = 0.f; }
    const float4* vT4 = (const float4*)vecsT;
    for (int d0 = 0; d0 < 64; d0 += 4) {
      float4 v0 = vT4[(d0 + 0) * 250 + t];
      float4 v1 = vT4[(d0 + 1) * 250 + t];
      float4 v2 = vT4[(d0 + 2) * 250 + t];
      float4 v3 = vT4[(d0 + 3) * 250 + t];
      #pragma unroll
      for (int rl = 0; rl < 8; ++rl) {
        float4 xv = *(const float4*)(&x_s[rl][d0]);
        acc0[rl] += xv.x * v0.x + xv.y * v1.x + xv.z * v2.x + xv.w * v3.x;
        acc1[rl] += xv.x * v0.y + xv.y * v1.y + xv.z * v2.y + xv.w * v3.y;
        acc2[rl] += xv.x * v0.z + xv.y * v1.z + xv.z * v2.z + xv.w * v3.z;
        acc3[rl] += xv.x * v0.w + xv.y * v1.w + xv.z * v2.w + xv.w * v3.w;
      }
    }
    #pragma unroll
    for (int rl = 0; rl < 8; ++rl) {
      float4 o; o.x = acc0[rl]; o.y = acc1[rl]; o.z = acc2[rl]; o.w = acc3[rl];
      *(float4*)(&xc_s[rl][4 * t]) = o;
    }
  }
  __syncthreads();

  // ---- phase 3: per-row softmax stats + KL_c (wave w handles rows w, w+4) ----
  {
    const int w = t >> 6, lane = t & 63;
    for (int rr = 0; rr < 2; ++rr) {
      int rl = w + rr * 4;
      int c3 = lane + 192;
      bool has = (c3 < 250);
      float4 va = *(const float4*)&xc_s[rl][4 * lane];
      float4 vb = *(const float4*)&xc_s[rl][4 * (lane + 64)];
      float4 vc = *(const float4*)&xc_s[rl][4 * (lane + 128)];
      float4 vd = has ? *(const float4*)&xc_s[rl][4 * c3]
                      : make_float4(-3.0e38f, -3.0e38f, -3.0e38f, -3.0e38f);
      float m = fmaxf(fmaxf(fmaxf(va.x, va.y), fmaxf(va.z, va.w)),
                      fmaxf(fmaxf(vb.x, vb.y), fmaxf(vb.z, vb.w)));
      m = fmaxf(m, fmaxf(fmaxf(vc.x, vc.y), fmaxf(vc.z, vc.w)));
      m = fmaxf(m, fmaxf(fmaxf(vd.x, vd.y), fmaxf(vd.z, vd.w)));
      #pragma unroll
      for (int off = 32; off > 0; off >>= 1) m = fmaxf(m, __shfl_xor(m, off));
      float s0 = 0.f, s1 = 0.f;
      #define ACC4(v) { float e; \
        e = __expf(v.x - m); s0 += e; s1 += e * v.x; \
        e = __expf(v.y - m); s0 += e; s1 += e * v.y; \
        e = __expf(v.z - m); s0 += e; s1 += e * v.z; \
        e = __expf(v.w - m); s0 += e; s1 += e * v.w; }
      ACC4(va) ACC4(vb) ACC4(vc)
      if (has) ACC4(vd)
      #undef ACC4
      #pragma unroll
      for (int off = 32; off > 0; off >>= 1) { s0 += __shfl_xor(s0, off); s1 += __shfl_xor(s1, off); }
      if (lane == 0) {
        float lse = m + __logf(s0);
        atomicAdd(&kl_s, s1 / s0 - lse + 6.9077552790f);   // - log(1/1000)
      }
    }
  }

  // ---- phase 4: per pair, gumbel noise + softmax((xc+g)/2) weights ----
  for (int p = 0; p < 4; ++p) {
    const int rA = p, rB = p + 4;
    const uint32_t rowA = (uint32_t)(pair0 + p);
    float tvA[4] = {0.f, 0.f, 0.f, 0.f}, tvB[4] = {0.f, 0.f, 0.f, 0.f};
    float mA = -3.0e38f, mB = -3.0e38f;
    #pragma unroll
    for (int k2 = 0; k2 < 4; ++k2) {
      int n = t + 256 * k2;
      if (n < NPTS) {
        uint32_t j0 = rowA * 1000u + (uint32_t)n;     // < 32768000 always
        uint32_t y0, y1;
        tf2x32(kc0, kc1, j0, j0 + 32768000u, y0, y1); // paired counters
        float ta = (xc_s[rA][n] + gumbel_from_bits(y0)) * 0.5f;
        float tb = (xc_s[rB][n] + gumbel_from_bits(y1)) * 0.5f;
        tvA[k2] = ta; tvB[k2] = tb;
        mA = fmaxf(mA, ta); mB = fmaxf(mB, tb);
      }
    }
    block_reduce2<true>(mA, mB, red_s, t);
    float sA = 0.f, sB = 0.f;
    #pragma unroll
    for (int k2 = 0; k2 < 4; ++k2) {
      int n = t + 256 * k2;
      if (n < NPTS) {
        float wa = __expf(tvA[k2] - mA);
        float wb = __expf(tvB[k2] - mB);
        xc_s[rA][n] = wa; xc_s[rB][n] = wb;
        sA += wa; sB += wb;
      }
    }
    block_reduce2<false>(sA, sB, red_s, t);
    if (t == 0) { invW_s[rA] = 1.f / sA; invW_s[rB] = 1.f / sB; }
  }
  __syncthreads();

  // ---- phase 4c: quantized_coord = (w . vecs) * invW ----
  {
    const int d = t & 63, rg = t >> 6;   // rg handles rows rg*2, rg*2+1
    const int r0 = rg * 2, r1 = rg * 2 + 1;
    float q0 = 0.f, q1 = 0.f;
    #pragma unroll 2
    for (int n0 = 0; n0 < NPTS; n0 += 4) {
      float v0 = vecs[(n0 + 0) * 64 + d];
      float v1 = vecs[(n0 + 1) * 64 + d];
      float v2 = vecs[(n0 + 2) * 64 + d];
      float v3 = vecs[(n0 + 3) * 64 + d];
      float4 wA = *(const float4*)&xc_s[r0][n0];
      float4 wB = *(const float4*)&xc_s[r1][n0];
      q0 += wA.x * v0 + wA.y * v1 + wA.z * v2 + wA.w * v3;
      q1 += wB.x * v0 + wB.y * v1 + wB.z * v2 + wB.w * v3;
    }
    int rowa = (r0 < 4) ? (pair0 + r0) : (pair0 + r0 - 4 + NROWS_HALF);
    int rowb = (r1 < 4) ? (pair0 + r1) : (pair0 + r1 - 4 + NROWS_HALF);
    out[QC_OFF + rowa * 64 + d] = q0 * invW_s[r0];
    out[QC_OFF + rowb * 64 + d] = q1 * invW_s[r1];
  }

  // ---- phase 5a: codebook logits xp = x . M^T (thread: row t>>5, m = t&31) ----
  {
    const int rl = t >> 5, m = t & 31;
    const float4* M4 = (const float4*)M;
    float a = 0.f;
    #pragma unroll
    for (int d0 = 0; d0 < 64; d0 += 4) {
      float4 xv = *(const float4*)&x_s[rl][d0];
      float4 mv = M4[m * 16 + (d0 >> 2)];
      a += xv.x * mv.x + xv.y * mv.y + xv.z * mv.z + xv.w * mv.w;
    }
    xp_s[rl][m] = a;
  }
  __syncthreads();

  // ---- phase 5b: per (row, k): KL_p, gumbel-softmax, q = ip . embK ----
  float (*q_s)[64] = x_s;   // reuse (x no longer needed)
  {
    const int rl = t >> 5, wi = t & 31;
    if (wi < 4) {
      const int k = wi;
      float xp[8];
      #pragma unroll
      for (int n = 0; n < 8; ++n) xp[n] = xp_s[rl][k * 8 + n];
      float m = xp[0];
      #pragma unroll
      for (int n = 1; n < 8; ++n) m = fmaxf(m, xp[n]);
      float s0 = 0.f, s1 = 0.f;
      #pragma unroll
      for (int n = 0; n < 8; ++n) { float e = __expf(xp[n] - m); s0 += e; s1 += e * xp[n]; }
      float lse = m + __logf(s0);
      atomicAdd(&kl_s, s1 / s0 - lse + 2.0794415417f);   // - log(1/8)
      // noise: rows <32768 use y0 of (j, j+1048576); rows >=32768 use y1
      uint32_t rowg = (rl < 4) ? (uint32_t)(pair0 + rl) : (uint32_t)(pair0 + rl - 4 + NROWS_HALF);
      uint32_t base = ((rl < 4) ? rowg : (rowg - (uint32_t)NROWS_HALF)) * 32u + (uint32_t)k * 8u;
      float tp[8], m2 = -3.0e38f;
      #pragma unroll
      for (int n = 0; n < 8; ++n) {
        uint32_t y0, y1;
        tf2x32(kp0, kp1, base + n, base + n + 1048576u, y0, y1);
        float g = gumbel_from_bits((rl < 4) ? y0 : y1);
        tp[n] = (xp[n] + g) * 0.5f;
        m2 = fmaxf(m2, tp[n]);
      }
      float wv[8], sw = 0.f;
      #pragma unroll
      for (int n = 0; n < 8; ++n) { wv[n] = __expf(tp[n] - m2); sw += wv[n]; }
      float inv = 1.0f / sw;
      #pragma unroll
      for (int e = 0; e < 16; ++e) {
        float acc = 0.f;
        #pragma unroll
        for (int n = 0; n < 8; ++n) acc += wv[n] * emb[(k * 8 + n) * 16 + e];
        q_s[rl][k * 16 + e] = acc * inv;
      }
    }
  }
  __syncthreads();

  // ---- copyout quantized (coalesced) + loss partial ----
  #pragma unroll
  for (int it = 0; it < 2; ++it) {
    int idx = it * 256 + t;
    int rl = idx >> 6, c = idx & 63;
    int row = (rl < 4) ? (pair0 + rl) : (pair0 + rl - 4 + NROWS_HALF);
    out[row * 64 + c] = q_s[rl][c];
  }
  if (t == 0) atomicAdd(loss_acc, kl_s);
}

__global__ void finalize_kernel(const float* __restrict__ loss_acc, float* __restrict__ out) {
  if (threadIdx.x == 0 && blockIdx.x == 0) out[LOSS_OFF] = loss_acc[0] * 0.2f;
}

extern "C" void kernel_launch(void* const* d_in, const int* in_sizes, int n_in,
                              void* d_out, int out_size, void* d_ws, size_t ws_size,
                              hipStream_t stream) {
  const float* inp  = (const float*)d_in[0];   // [32,2048,64]
  const float* lw   = (const float*)d_in[1];   // [64,3]
  const float* lb   = (const float*)d_in[2];   // [64]
  const float* emb  = (const float*)d_in[3];   // [32,16] normalized
  const float* lws  = (const float*)d_in[4];   // [4,16,64]
  float* out = (float*)d_out;
  float* ws  = (float*)d_ws;

  // JAX PRNG keys: key(42) -> [0,42]; split = threefry over iota(4)
  uint32_t a0, b0, a1, b1;
  tf2x32(0u, 42u, 0u, 2u, a0, b0);
  tf2x32(0u, 42u, 1u, 3u, a1, b1);
  const uint32_t kc0 = a0, kc1 = a1;   // coord-noise key
  const uint32_t kp0 = b0, kp1 = b1;   // codebook-noise key

  setup_kernel<<<259, 256, 0, stream>>>(lw, lb, emb, lws, ws);
  fused_kernel<<<8192, 256, 0, stream>>>(inp, emb, ws, out, ws + WS_LOSS,
                                         kc0, kc1, kp0, kp1);
  finalize_kernel<<<1, 64, 0, stream>>>(ws + WS_LOSS, out);
}

// Round 2
// 502.186 us; speedup vs baseline: 1.5105x; 1.5105x over previous
//
#include <hip/hip_runtime.h>
#include <cstdint>

#define NROWS_HALF 32768
#define NPTS 1000
#define QC_OFF 4194304            // quantized_coord offset in d_out (floats)
#define LOSS_OFF 8388608          // loss offset in d_out (floats)

// ws layout in ushort units (bf16 stored as raw ushort):
//   [0,64512)        Vh_nd [1008][64]   (rows 1000..1007 zero)
//   [64512,129024)   Vl_nd [1008][64]
//   [129024,194560)  VhT   [64][1024]   (cols 1000..1023 zero)
//   [194560,260096)  VlT   [64][1024]
//   byte 520192: fp32 loss accumulator   (total 520196 B)
#define U_VH_ND 0
#define U_VL_ND 64512
#define U_VHT   129024
#define U_VLT   194560
#define WS_LOSS_BYTE 520192

#define XC_STRIDE 1044            // floats; 1044%32==20 -> <=2-way LDS bank aliasing
#define X_STRIDE 68

typedef short short8 __attribute__((ext_vector_type(8)));
typedef float float4v __attribute__((ext_vector_type(4)));

#define MFMA16(a, b, c) __builtin_amdgcn_mfma_f32_16x16x32_bf16((a), (b), (c), 0, 0, 0)

// ---------------- Threefry-2x32 (20 rounds), matches JAX ----------------
__host__ __device__ __forceinline__ void tf2x32(uint32_t k0, uint32_t k1,
                                                uint32_t x0, uint32_t x1,
                                                uint32_t& o0, uint32_t& o1) {
  const uint32_t k2 = k0 ^ k1 ^ 0x1BD11BDAu;
#define TF_R(r) { x0 += x1; x1 = (x1 << (r)) | (x1 >> (32 - (r))); x1 ^= x0; }
  x0 += k0; x1 += k1;
  TF_R(13) TF_R(15) TF_R(26) TF_R(6)
  x0 += k1; x1 += k2 + 1u;
  TF_R(17) TF_R(29) TF_R(16) TF_R(24)
  x0 += k2; x1 += k0 + 2u;
  TF_R(13) TF_R(15) TF_R(26) TF_R(6)
  x0 += k0; x1 += k1 + 3u;
  TF_R(17) TF_R(29) TF_R(16) TF_R(24)
  x0 += k1; x1 += k2 + 4u;
  TF_R(13) TF_R(15) TF_R(26) TF_R(6)
  x0 += k2; x1 += k0 + 5u;
#undef TF_R
  o0 = x0; o1 = x1;
}

// gumbel(bits) = -log(-log(u + 1e-20) + 1e-20), u = (bits>>9 | 1.0f) - 1.0f
__device__ __forceinline__ float gumbel_from_bits(uint32_t bits) {
  const uint32_t mant = bits >> 9;
  const float u = __uint_as_float(mant | 0x3f800000u) - 1.0f;
  const float delta = (float)(8388608u - mant) * 1.1920928955078125e-7f;
  float l;
  if (delta < 0.00390625f) {
    l = -(delta + 0.5f * delta * delta + 0.33333333f * delta * delta * delta);
  } else {
    l = __logf(u + 1e-20f);
  }
  return -__logf(-l + 1e-20f);
}

// split fp32 pair -> packed bf16 hi pair + bf16 lo pair (truncation; lo captures residual)
__device__ __forceinline__ void split2(float f0, float f1, uint32_t& hi, uint32_t& lo) {
  uint32_t u0 = __float_as_uint(f0), u1 = __float_as_uint(f1);
  hi = (u0 >> 16) | (u1 & 0xFFFF0000u);
  float l0 = f0 - __uint_as_float(u0 & 0xFFFF0000u);
  float l1 = f1 - __uint_as_float(u1 & 0xFFFF0000u);
  lo = (__float_as_uint(l0) >> 16) | (__float_as_uint(l1) & 0xFFFF0000u);
}

__device__ __forceinline__ void split8(const float* p, short8& hi, short8& lo) {
  float4 f0 = *(const float4*)p;
  float4 f1 = *(const float4*)(p + 4);
  union { uint32_t u[4]; short8 s; } H, L;
  split2(f0.x, f0.y, H.u[0], L.u[0]);
  split2(f0.z, f0.w, H.u[1], L.u[1]);
  split2(f1.x, f1.y, H.u[2], L.u[2]);
  split2(f1.z, f1.w, H.u[3], L.u[3]);
  hi = H.s; lo = L.s;
}

__device__ __forceinline__ short8 as_s8(uint4 v) {
  union { uint4 u; short8 s; } c; c.u = v; return c.s;
}

// grid vec value v(n,c)
__device__ __forceinline__ float grid_vec(int n, int c, const float* __restrict__ lw,
                                          const float* __restrict__ lb) {
  int jx = (n / 10) % 10, iy = n / 100, kz = n % 10;
  const double step = 1.5 / 9.0;
  float gx = (float)(jx * step), gy = (float)(iy * step), gz = (float)(kz * step);
  return gx * lw[c * 3 + 0] + gy * lw[c * 3 + 1] + gz * lw[c * 3 + 2] + lb[c];
}

// ---------------- setup: bf16 split V in both layouts, loss=0 ----------------
__global__ void setup_kernel(const float* __restrict__ lw, const float* __restrict__ lb,
                             ushort* __restrict__ wsu) {
  int idx = blockIdx.x * 256 + threadIdx.x;
  if (idx < 64512) {
    int n = idx >> 6, c = idx & 63;
    float v = (n < NPTS) ? grid_vec(n, c, lw, lb) : 0.f;
    uint32_t u = __float_as_uint(v);
    float fl = v - __uint_as_float(u & 0xFFFF0000u);
    wsu[U_VH_ND + idx] = (ushort)(u >> 16);
    wsu[U_VL_ND + idx] = (ushort)(__float_as_uint(fl) >> 16);
  } else if (idx < 130048) {
    int i2 = idx - 64512;              // d*1024 + n
    int d = i2 >> 10, n = i2 & 1023;
    float v = (n < NPTS) ? grid_vec(n, d, lw, lb) : 0.f;
    uint32_t u = __float_as_uint(v);
    float fl = v - __uint_as_float(u & 0xFFFF0000u);
    wsu[U_VHT + i2] = (ushort)(u >> 16);
    wsu[U_VLT + i2] = (ushort)(__float_as_uint(fl) >> 16);
  } else if (idx == 130048) {
    *(float*)((char*)wsu + WS_LOSS_BYTE) = 0.f;
  }
}

// ---------------- fused main kernel: 4096 blocks x 256 ----------------
// Block handles 16 local rows: lr 0..7 -> g0+lr, lr 8..15 -> g0+lr-8+32768 (threefry pairs)
__global__ __launch_bounds__(256) void fused_kernel(
    const float* __restrict__ inp, const float* __restrict__ emb,
    const float* __restrict__ lws, const ushort* __restrict__ wsu,
    float* __restrict__ out, float* __restrict__ loss_acc,
    uint32_t kc0, uint32_t kc1, uint32_t kp0, uint32_t kp1) {

  __shared__ float xc_s[16 * XC_STRIDE];   // logits -> gumbel weights (fp32)
  __shared__ float x_s[16 * X_STRIDE];     // input rows; later q output
  __shared__ float xp_s[16 * 32];          // codebook logits
  __shared__ float invW_s[16];
  __shared__ float kl_s;

  const int t = threadIdx.x;
  const int lane = t & 63;
  const int w = t >> 6;
  const int quad = lane >> 4;
  const int mn = lane & 15;
  const int g0 = blockIdx.x * 8;

  if (t == 0) kl_s = 0.f;

  // ---- load 16 input rows ----
  #pragma unroll
  for (int it = 0; it < 4; ++it) {
    int idx = it * 256 + t;
    int rl = idx >> 6, d = idx & 63;
    int row = (rl < 8) ? (g0 + rl) : (g0 + rl - 8 + NROWS_HALF);
    x_s[rl * X_STRIDE + d] = inp[row * 64 + d];
  }
  __syncthreads();

  // ---- GEMM1 (MFMA): logits[16][1008] = X[16][64] . Vt[64][1008], split bf16 ----
  {
    short8 ah[2], al[2];
    #pragma unroll
    for (int s = 0; s < 2; ++s)
      split8(&x_s[mn * X_STRIDE + s * 32 + quad * 8], ah[s], al[s]);
    const ushort* Vh = wsu + U_VH_ND;
    const ushort* Vl = wsu + U_VL_ND;
    for (int j = w; j < 63; j += 4) {
      const int nb = (j * 16 + mn) * 64 + quad * 8;
      uint4 bh0 = *(const uint4*)(Vh + nb);
      uint4 bl0 = *(const uint4*)(Vl + nb);
      uint4 bh1 = *(const uint4*)(Vh + nb + 32);
      uint4 bl1 = *(const uint4*)(Vl + nb + 32);
      float4v acc = {0.f, 0.f, 0.f, 0.f};
      acc = MFMA16(ah[0], as_s8(bh0), acc);
      acc = MFMA16(ah[0], as_s8(bl0), acc);
      acc = MFMA16(al[0], as_s8(bh0), acc);
      acc = MFMA16(ah[1], as_s8(bh1), acc);
      acc = MFMA16(ah[1], as_s8(bl1), acc);
      acc = MFMA16(al[1], as_s8(bh1), acc);
      #pragma unroll
      for (int r = 0; r < 4; ++r)
        xc_s[(quad * 4 + r) * XC_STRIDE + j * 16 + mn] = acc[r];
    }
  }
  __syncthreads();

  // ---- phase 3: softmax stats + KL_c (wave w owns rows w, w+4, w+8, w+12) ----
  #pragma unroll
  for (int rr = 0; rr < 4; ++rr) {
    int rl = w + rr * 4;
    const float* rp = &xc_s[rl * XC_STRIDE];
    float4 va = *(const float4*)(rp + 4 * lane);
    float4 vb = *(const float4*)(rp + 4 * lane + 256);
    float4 vc = *(const float4*)(rp + 4 * lane + 512);
    bool has = lane < 58;
    float4 vd = has ? *(const float4*)(rp + 4 * lane + 768)
                    : make_float4(-3.0e38f, -3.0e38f, -3.0e38f, -3.0e38f);
    float m = fmaxf(fmaxf(fmaxf(va.x, va.y), fmaxf(va.z, va.w)),
                    fmaxf(fmaxf(vb.x, vb.y), fmaxf(vb.z, vb.w)));
    m = fmaxf(m, fmaxf(fmaxf(vc.x, vc.y), fmaxf(vc.z, vc.w)));
    m = fmaxf(m, fmaxf(fmaxf(vd.x, vd.y), fmaxf(vd.z, vd.w)));
    #pragma unroll
    for (int off = 32; off > 0; off >>= 1) m = fmaxf(m, __shfl_xor(m, off));
    float s0 = 0.f, s1 = 0.f;
    #define ACC4(v) { float e; \
      e = __expf(v.x - m); s0 += e; s1 += e * v.x; \
      e = __expf(v.y - m); s0 += e; s1 += e * v.y; \
      e = __expf(v.z - m); s0 += e; s1 += e * v.z; \
      e = __expf(v.w - m); s0 += e; s1 += e * v.w; }
    ACC4(va) ACC4(vb) ACC4(vc) ACC4(vd)
    #undef ACC4
    #pragma unroll
    for (int off = 32; off > 0; off >>= 1) { s0 += __shfl_xor(s0, off); s1 += __shfl_xor(s1, off); }
    if (lane == 0) {
      float lse = m + __logf(s0);
      atomicAdd(&kl_s, s1 / s0 - lse + 6.9077552790f);   // - log(1/1000)
    }
  }

  // ---- phase 4: gumbel weights, wave-local (pairs (w,w+8),(w+4,w+12)) ----
  #pragma unroll
  for (int pp = 0; pp < 2; ++pp) {
    const int p = w + 4 * pp;
    const int rA = p, rB = p + 8;
    const uint32_t rowA = (uint32_t)(g0 + p);
    float* rpA = &xc_s[rA * XC_STRIDE];
    float* rpB = &xc_s[rB * XC_STRIDE];
    float tvA[16], tvB[16];
    float mA = -3.0e38f, mB = -3.0e38f;
    #pragma unroll
    for (int jj = 0; jj < 16; ++jj) {
      int n = lane + 64 * jj;
      if (n < NPTS) {
        uint32_t j0 = rowA * 1000u + (uint32_t)n;
        uint32_t y0, y1;
        tf2x32(kc0, kc1, j0, j0 + 32768000u, y0, y1);
        float ta = (rpA[n] + gumbel_from_bits(y0)) * 0.5f;
        float tb = (rpB[n] + gumbel_from_bits(y1)) * 0.5f;
        tvA[jj] = ta; tvB[jj] = tb;
        mA = fmaxf(mA, ta); mB = fmaxf(mB, tb);
      }
    }
    #pragma unroll
    for (int off = 32; off > 0; off >>= 1) {
      mA = fmaxf(mA, __shfl_xor(mA, off));
      mB = fmaxf(mB, __shfl_xor(mB, off));
    }
    float sA = 0.f, sB = 0.f;
    #pragma unroll
    for (int jj = 0; jj < 16; ++jj) {
      int n = lane + 64 * jj;
      if (n < NPTS) {
        float wa = __expf(tvA[jj] - mA);
        float wb = __expf(tvB[jj] - mB);
        rpA[n] = wa; rpB[n] = wb;
        sA += wa; sB += wb;
      }
    }
    #pragma unroll
    for (int off = 32; off > 0; off >>= 1) { sA += __shfl_xor(sA, off); sB += __shfl_xor(sB, off); }
    if (lane == 0) { invW_s[rA] = 1.f / sA; invW_s[rB] = 1.f / sB; }
    if (lane < 24) { rpA[1000 + lane] = 0.f; rpB[1000 + lane] = 0.f; }  // zero MFMA pad
  }
  __syncthreads();

  // ---- GEMM2 (MFMA): qc[16][64] = W[16][1024] . V[1024][64]; wave w -> d-tile w ----
  {
    const ushort* VhT = wsu + U_VHT;
    const ushort* VlT = wsu + U_VLT;
    const int dq = w * 16 + mn;                    // output d column
    const float* wr = &xc_s[mn * XC_STRIDE + quad * 8];
    float4v acc = {0.f, 0.f, 0.f, 0.f};
    for (int s = 0; s < 32; ++s) {
      short8 ha, la;
      split8(wr + s * 32, ha, la);
      uint4 bh = *(const uint4*)(VhT + dq * 1024 + s * 32 + quad * 8);
      uint4 bl = *(const uint4*)(VlT + dq * 1024 + s * 32 + quad * 8);
      acc = MFMA16(ha, as_s8(bh), acc);
      acc = MFMA16(ha, as_s8(bl), acc);
      acc = MFMA16(la, as_s8(bh), acc);
    }
    #pragma unroll
    for (int r = 0; r < 4; ++r) {
      int m = quad * 4 + r;
      int grow = (m < 8) ? (g0 + m) : (g0 + m - 8 + NROWS_HALF);
      out[QC_OFF + grow * 64 + dq] = acc[r] * invW_s[m];
    }
  }
  __syncthreads();   // all GEMM2 reads of xc done -> can alias M into xc

  // ---- M[32][64] = sum_e embK[k,n,e]*lin_ws[k,e,d]  (aliased into xc_s) ----
  float* M_s = xc_s;
  #pragma unroll
  for (int e = 0; e < 8; ++e) {
    int idx = e * 256 + t;     // 2048 entries
    int mm = idx >> 6, d = idx & 63, k = mm >> 3;
    float a = 0.f;
    #pragma unroll
    for (int ee = 0; ee < 16; ++ee) a += emb[mm * 16 + ee] * lws[(k * 16 + ee) * 64 + d];
    M_s[idx] = a;
  }
  __syncthreads();

  // ---- phase 5a: xp = x . M^T (thread: rows t>>5 and (t>>5)+8, m32 = t&31) ----
  {
    const int rl = t >> 5, m32 = t & 31;
    float a0 = 0.f, a1 = 0.f;
    #pragma unroll
    for (int d0 = 0; d0 < 64; d0 += 4) {
      float4 mv = *(const float4*)&M_s[m32 * 64 + d0];
      float4 x0 = *(const float4*)&x_s[rl * X_STRIDE + d0];
      float4 x1 = *(const float4*)&x_s[(rl + 8) * X_STRIDE + d0];
      a0 += x0.x * mv.x + x0.y * mv.y + x0.z * mv.z + x0.w * mv.w;
      a1 += x1.x * mv.x + x1.y * mv.y + x1.z * mv.z + x1.w * mv.w;
    }
    xp_s[rl * 32 + m32] = a0;
    xp_s[(rl + 8) * 32 + m32] = a1;
  }
  __syncthreads();

  // ---- phase 5b: per (pair p, k): KL_p, gumbel-softmax, q = ip . embK ----
  float* q_s = x_s;   // x dead after 5a
  if (t < 32) {
    const int p = t >> 2, k = t & 3;
    const int rA = p, rB = p + 8;
    float xpA[8], xpB[8];
    #pragma unroll
    for (int n = 0; n < 8; ++n) {
      xpA[n] = xp_s[rA * 32 + k * 8 + n];
      xpB[n] = xp_s[rB * 32 + k * 8 + n];
    }
    float mA = xpA[0], mB = xpB[0];
    #pragma unroll
    for (int n = 1; n < 8; ++n) { mA = fmaxf(mA, xpA[n]); mB = fmaxf(mB, xpB[n]); }
    float s0A = 0.f, s1A = 0.f, s0B = 0.f, s1B = 0.f;
    #pragma unroll
    for (int n = 0; n < 8; ++n) {
      float eA = __expf(xpA[n] - mA); s0A += eA; s1A += eA * xpA[n];
      float eB = __expf(xpB[n] - mB); s0B += eB; s1B += eB * xpB[n];
    }
    atomicAdd(&kl_s, (s1A / s0A - (mA + __logf(s0A)) + 2.0794415417f) +
                     (s1B / s0B - (mB + __logf(s0B)) + 2.0794415417f));
    uint32_t base = (uint32_t)(g0 + p) * 32u + (uint32_t)k * 8u;
    float tA[8], tB[8], m2A = -3.0e38f, m2B = -3.0e38f;
    #pragma unroll
    for (int n = 0; n < 8; ++n) {
      uint32_t y0, y1;
      tf2x32(kp0, kp1, base + n, base + n + 1048576u, y0, y1);
      tA[n] = (xpA[n] + gumbel_from_bits(y0)) * 0.5f;
      tB[n] = (xpB[n] + gumbel_from_bits(y1)) * 0.5f;
      m2A = fmaxf(m2A, tA[n]); m2B = fmaxf(m2B, tB[n]);
    }
    float wvA[8], wvB[8], swA = 0.f, swB = 0.f;
    #pragma unroll
    for (int n = 0; n < 8; ++n) {
      wvA[n] = __expf(tA[n] - m2A); swA += wvA[n];
      wvB[n] = __expf(tB[n] - m2B); swB += wvB[n];
    }
    float invA = 1.0f / swA, invB = 1.0f / swB;
    #pragma unroll
    for (int e = 0; e < 16; ++e) {
      float aA = 0.f, aB = 0.f;
      #pragma unroll
      for (int n = 0; n < 8; ++n) {
        float ev = emb[(k * 8 + n) * 16 + e];
        aA += wvA[n] * ev; aB += wvB[n] * ev;
      }
      q_s[rA * X_STRIDE + k * 16 + e] = aA * invA;
      q_s[rB * X_STRIDE + k * 16 + e] = aB * invB;
    }
  }
  __syncthreads();

  // ---- copyout quantized (coalesced) + loss partial ----
  #pragma unroll
  for (int it = 0; it < 4; ++it) {
    int idx = it * 256 + t;
    int rl = idx >> 6, c = idx & 63;
    int row = (rl < 8) ? (g0 + rl) : (g0 + rl - 8 + NROWS_HALF);
    out[row * 64 + c] = q_s[rl * X_STRIDE + c];
  }
  if (t == 0) atomicAdd(loss_acc, kl_s);
}

__global__ void finalize_kernel(const float* __restrict__ loss_acc, float* __restrict__ out) {
  if (threadIdx.x == 0 && blockIdx.x == 0) out[LOSS_OFF] = loss_acc[0] * 0.2f;
}

extern "C" void kernel_launch(void* const* d_in, const int* in_sizes, int n_in,
                              void* d_out, int out_size, void* d_ws, size_t ws_size,
                              hipStream_t stream) {
  const float* inp  = (const float*)d_in[0];   // [32,2048,64]
  const float* lw   = (const float*)d_in[1];   // [64,3]
  const float* lb   = (const float*)d_in[2];   // [64]
  const float* emb  = (const float*)d_in[3];   // [32,16] normalized
  const float* lws  = (const float*)d_in[4];   // [4,16,64]
  float* out = (float*)d_out;
  ushort* wsu = (ushort*)d_ws;
  float* loss = (float*)((char*)d_ws + WS_LOSS_BYTE);

  // JAX PRNG keys: key(42) -> [0,42]; split = threefry over iota(4)
  uint32_t a0, b0, a1, b1;
  tf2x32(0u, 42u, 0u, 2u, a0, b0);
  tf2x32(0u, 42u, 1u, 3u, a1, b1);
  const uint32_t kc0 = a0, kc1 = a1;   // coord-noise key
  const uint32_t kp0 = b0, kp1 = b1;   // codebook-noise key

  setup_kernel<<<509, 256, 0, stream>>>(lw, lb, wsu);
  fused_kernel<<<4096, 256, 0, stream>>>(inp, emb, lws, wsu, out, loss,
                                         kc0, kc1, kp0, kp1);
  finalize_kernel<<<1, 64, 0, stream>>>(loss, out);
}